// Round 3
// baseline (1078.695 us; speedup 1.0000x reference)
//
#include <hip/hip_runtime.h>
#include <math.h>

// ConvT3d(32->64,k3,s2,p1,op1) + bias + 1 + LN(C=64) + AvgPool2^3 + GELU, fused.
//
// R2 structure: rows=co MFMA orientation. D = W * X with A=weights (M=16 co per
// subtile s, 4 subtiles = 64 co), B=x (N=16 pooled positions), K=32 ci.
// Per lane the 16 accumulators are ALL 64 channels of ONE position ->
// LayerNorm = in-register sums + shfl_xor(16/32). No per-class LDS round trip.
// Waves specialize by parity class (tap counts {8},{4,4},{4,2},{1,2,2}) so
// weight fragments stay in registers (<=32 short8 = 128 VGPR).
// Pool over the 8 classes via ds_add_f32 into [co][pos] (pad 34 -> 2-way free).
// Barriers: 4 per hp-iteration (vs 17 in R1).

typedef __attribute__((ext_vector_type(8))) short short8;
typedef __attribute__((ext_vector_type(4))) float f32x4;

template<int V> struct IC { static constexpr int value = V; };

__device__ __forceinline__ unsigned short f2bf(float v) {
    unsigned int b = __float_as_uint(v);
    return (unsigned short)((b + 0x7fffu + ((b >> 16) & 1u)) >> 16);
}

// weight prepack: wpack[tap][co][ci] bf16, tap = kd*9+kh*3+kw
__global__ void pack_w(const float* __restrict__ w, unsigned short* __restrict__ wp) {
    int t = blockIdx.x * 256 + threadIdx.x;
    if (t >= 27 * 64 * 32) return;
    int ci = t & 31, co = (t >> 5) & 63, tap = t >> 11;
    wp[(tap * 64 + co) * 32 + ci] = f2bf(w[(ci * 64 + co) * 27 + tap]);
}

#define XS_ROWSTRIDE 34              // halfwords per [w] row (32 ci + 2 pad)
#define POOL_OFF (64 * 34)           // corr[] starts here

template<int N0, int N1, int N2>
__device__ __forceinline__ void body(
    const int (&TT)[8],
    const float* __restrict__ x, const unsigned short* __restrict__ wpack,
    const float* __restrict__ bias, const float* __restrict__ gamma,
    const float* __restrict__ beta, float* __restrict__ out,
    float* sbuf, unsigned short* xs, float* poolL,
    int n, int dp, int hq, int t)
{
    constexpr int NT = N0 + N1 + N2;
    const int lane = t & 63, l15 = lane & 15, quad = lane >> 4;

    // ---- weight A-frags in registers: Wf[tap][s], co = s*16+l15, ci = quad*8+j ----
    short8 Wf[NT][4];
#pragma unroll
    for (int u = 0; u < NT; ++u)
#pragma unroll
        for (int s = 0; s < 4; ++s)
            Wf[u][s] = *(const short8*)(wpack + (TT[u] * 64 + s * 16 + l15) * 32 + quad * 8);

    // xs base offset per tap (delta = k-component >> 1, valid for this parity class)
    int xbase[NT];
#pragma unroll
    for (int u = 0; u < NT; ++u) {
        int tap = TT[u];
        int dd = (tap / 9) >> 1, hh = ((tap / 3) % 3) >> 1, dw = (tap % 3) >> 1;
        xbase[u] = ((dd * 2 + hh) * 33 + dw) * XS_ROWSTRIDE;
    }

    // bias (+1 SUM_WEIGHT) per this lane's 16 channels: co = s*16 + quad*4 + r
    f32x4 bias4[4];
#pragma unroll
    for (int s = 0; s < 4; ++s)
#pragma unroll
        for (int r = 0; r < 4; ++r)
            bias4[s][r] = bias[s * 16 + quad * 4 + r] + 1.0f;

    // epilogue constants: thread t -> pos = t&31, channels ecog*8..+7
    const int epos = t & 31, ecog = t >> 5;
    float g8[8], bb[8];
#pragma unroll
    for (int k = 0; k < 8; ++k) {
        g8[k] = 0.125f * gamma[ecog * 8 + k];
        bb[k] = beta[ecog * 8 + k];
    }

    for (int i = 0; i < 4; ++i) {
        const int hp = hq * 4 + i;

        // ---- pass 1: coalesced global -> sbuf f32 [ci][sp] ; zero pool ----
        for (int idx = t; idx < 32 * 132; idx += 256) {
            int sp = idx % 132, ci = idx / 132;
            int dd = sp / 66, rem = sp - dd * 66, hh = rem / 33, ww = rem - hh * 33;
            int id = dp + dd, ih = hp + hh;
            float v = 0.f;
            if (ww < 32 && ih < 32 && id < 16)
                v = x[((n * 32 + ci) * 16 + id) * 1024 + ih * 32 + ww];
            sbuf[ci * 133 + sp] = v;
        }
        for (int idx = t; idx < POOL_OFF + 32; idx += 256) poolL[idx] = 0.f;
        __syncthreads();

        // ---- pass 2: transpose -> xs bf16 [(dd*2+hh)*33+w][ci], stride 34 ----
        for (int idx = t; idx < 2112; idx += 256) {
            int ci2 = idx & 15, rw = idx >> 4;          // rw in [0,132)
            int w = rw % 33, rr = rw / 33;
            float lo = sbuf[(2 * ci2) * 133 + rw];
            float hi = sbuf[(2 * ci2 + 1) * 133 + rw];
            unsigned int p = (unsigned int)f2bf(lo) | ((unsigned int)f2bf(hi) << 16);
            ((unsigned int*)xs)[(rr * 33 + w) * (XS_ROWSTRIDE / 2) + ci2] = p;
        }
        __syncthreads();

        // ---- compute: per position-group, my classes, in-register LN ----
#pragma unroll
        for (int g = 0; g < 2; ++g) {
            const int posoff = (g * 16 + l15) * XS_ROWSTRIDE + quad * 8;
            f32x4 pool4[4];
#pragma unroll
            for (int s = 0; s < 4; ++s) pool4[s] = (f32x4)0.f;

            auto one_class = [&](auto UBc, auto NTAPc) {
                constexpr int UB = decltype(UBc)::value;
                constexpr int NTAP = decltype(NTAPc)::value;
                f32x4 acc[4];
#pragma unroll
                for (int s = 0; s < 4; ++s) acc[s] = bias4[s];
#pragma unroll
                for (int uu = 0; uu < NTAP; ++uu) {
                    const unsigned short* bp = xs + xbase[UB + uu] + posoff;
                    union { int4 iv; short8 s8; } xf;
                    xf.iv.x = *(const int*)(bp + 0);
                    xf.iv.y = *(const int*)(bp + 2);
                    xf.iv.z = *(const int*)(bp + 4);
                    xf.iv.w = *(const int*)(bp + 6);
#pragma unroll
                    for (int s = 0; s < 4; ++s)
                        acc[s] = __builtin_amdgcn_mfma_f32_16x16x32_bf16(
                            Wf[UB + uu][s], xf.s8, acc[s], 0, 0, 0);
                }
                float s1 = 0.f, s2 = 0.f;
#pragma unroll
                for (int s = 0; s < 4; ++s)
#pragma unroll
                    for (int r = 0; r < 4; ++r) {
                        float v = acc[s][r];
                        s1 += v; s2 = fmaf(v, v, s2);
                    }
                s1 += __shfl_xor(s1, 16); s2 += __shfl_xor(s2, 16);
                s1 += __shfl_xor(s1, 32); s2 += __shfl_xor(s2, 32);
                float mean = s1 * (1.f / 64.f);
                float var = fmaf(mean, -mean, s2 * (1.f / 64.f));
                float rstd = rsqrtf(var + 1e-5f);
#pragma unroll
                for (int s = 0; s < 4; ++s)
#pragma unroll
                    for (int r = 0; r < 4; ++r)
                        pool4[s][r] = fmaf(acc[s][r], rstd, pool4[s][r]);
                if (quad == 0)
                    atomicAdd(&poolL[POOL_OFF + g * 16 + l15], mean * rstd);
            };

            one_class(IC<0>{}, IC<N0>{});
            if constexpr (N1 > 0) one_class(IC<N0>{}, IC<N1>{});
            if constexpr (N2 > 0) one_class(IC<N0 + N1>{}, IC<N2>{});

#pragma unroll
            for (int s = 0; s < 4; ++s)
#pragma unroll
                for (int r = 0; r < 4; ++r)
                    atomicAdd(&poolL[(s * 16 + quad * 4 + r) * 34 + g * 16 + l15],
                              pool4[s][r]);
        }
        __syncthreads();

        // ---- epilogue: pooled = (pool - corr)/8, gamma/beta, GELU, store ----
        {
            float corr = poolL[POOL_OFF + epos];
#pragma unroll
            for (int k = 0; k < 8; ++k) {
                int co = ecog * 8 + k;
                float v = poolL[co * 34 + epos];
                float y = fmaf(v, g8[k], fmaf(-corr, g8[k], bb[k]));
                float u = 0.7978845608028654f * fmaf(0.044715f * y, y * y, y);
                float gg = y / (1.f + __expf(-2.f * u));
                out[((n * 64 + co) * 16 + dp) * 1024 + hp * 32 + epos] = gg;
            }
        }
        __syncthreads();   // protect poolL/xs/sbuf for next iteration
    }
}

__global__ __launch_bounds__(256, 2) void conv_fused(
    const float* __restrict__ x, const unsigned short* __restrict__ wpack,
    const float* __restrict__ bias, const float* __restrict__ gamma,
    const float* __restrict__ beta, float* __restrict__ out)
{
    __shared__ float sbuf[32 * 133];
    __shared__ unsigned short xs[4 * 33 * XS_ROWSTRIDE];
    __shared__ float poolL[POOL_OFF + 32];

    const int t = threadIdx.x;
    const int wv = t >> 6;
    const int b = blockIdx.x;        // 4096 = 32n x 16dp x 8hq
    const int hq = b & 7;
    const int dp = (b >> 3) & 15;
    const int n = b >> 7;

    // class -> tap lists (tap = kd*9+kh*3+kw). Parity class (pd,ph,pw):
    // c7={0,2,6,8,18,20,24,26} c3={9,11,15,17} c5={3,5,21,23}
    // c6={1,7,19,25} c1={12,14} c0={13} c2={10,16} c4={4,22}
    if (wv == 0) {
        constexpr int TT[8] = {0, 2, 6, 8, 18, 20, 24, 26};
        body<8, 0, 0>(TT, x, wpack, bias, gamma, beta, out, sbuf, xs, poolL, n, dp, hq, t);
    } else if (wv == 1) {
        constexpr int TT[8] = {9, 11, 15, 17, 3, 5, 21, 23};
        body<4, 4, 0>(TT, x, wpack, bias, gamma, beta, out, sbuf, xs, poolL, n, dp, hq, t);
    } else if (wv == 2) {
        constexpr int TT[8] = {1, 7, 19, 25, 12, 14, 13, 13};
        body<4, 2, 0>(TT, x, wpack, bias, gamma, beta, out, sbuf, xs, poolL, n, dp, hq, t);
    } else {
        constexpr int TT[8] = {13, 10, 16, 4, 22, 13, 13, 13};
        body<1, 2, 2>(TT, x, wpack, bias, gamma, beta, out, sbuf, xs, poolL, n, dp, hq, t);
    }
}

// ---- fp32 fallback (R0 path) if workspace is too small for wpack ----
__global__ __launch_bounds__(256) void fused_fallback(
    const float* __restrict__ x, const float* __restrict__ w,
    const float* __restrict__ bias, const float* __restrict__ gamma,
    const float* __restrict__ beta, float* __restrict__ out)
{
    __shared__ __align__(16) float xs_lds[128 * 20];
    __shared__ float conv_lds[128 * 65];
    float* stats = xs_lds;

    const int t = threadIdx.x;
    const int b = blockIdx.x;
    const int wq = b & 1;
    const int hp = (b >> 1) & 31;
    const int dp = (b >> 6) & 15;
    const int n = b >> 10;

    for (int k = 0; k < 10; ++k) {
        int idx = t + k * 256;
        int col = idx % 20, r = idx / 20;
        int hh = r & 1, ddv = (r >> 1) & 1, ci = r >> 2;
        int iw = wq * 16 + col, ih = hp + hh, id = dp + ddv;
        float v = 0.f;
        if (col < 17 && iw < 32 && ih < 32 && id < 16)
            v = x[(((n * 32 + ci) * 16 + id) * 32 + ih) * 32 + iw];
        xs_lds[idx] = v;
    }
    __syncthreads();

    const int co = t & 63;
    const int sg = t >> 6;
    const float bco = bias[co] + 1.0f;

    for (int dd = 0; dd < 2; ++dd)
        for (int hh = 0; hh < 2; ++hh) {
            float acc[8];
#pragma unroll
            for (int j = 0; j < 8; ++j) acc[j] = 0.f;
            const int ndt = dd ? 2 : 1, nht = hh ? 2 : 1;
            for (int itp = 0; itp < ndt; ++itp) {
                const int kd = dd ? (itp ? 2 : 0) : 1;
                const int idl = dd ? itp : 0;
                for (int jt = 0; jt < nht; ++jt) {
                    const int kh = hh ? (jt ? 2 : 0) : 1;
                    const int ihl = hh ? jt : 0;
                    const int kidx = kd * 3 + kh;
#pragma unroll 4
                    for (int ci = 0; ci < 32; ++ci) {
                        const float* wp0 = w + (ci * 64 + co) * 27 + kidx * 3;
                        float w0 = wp0[0], w1 = wp0[1], w2 = wp0[2];
                        const float* xr = &xs_lds[(ci * 4 + idl * 2 + ihl) * 20 + sg * 4];
                        float4 xa = *(const float4*)xr;
                        float x4 = xr[4];
                        acc[0] += xa.x * w1;
                        acc[1] += xa.x * w0 + xa.y * w2;
                        acc[2] += xa.y * w1;
                        acc[3] += xa.y * w0 + xa.z * w2;
                        acc[4] += xa.z * w1;
                        acc[5] += xa.z * w0 + xa.w * w2;
                        acc[6] += xa.w * w1;
                        acc[7] += xa.w * w0 + x4 * w2;
                    }
                }
            }
            const int posb = (dd * 2 + hh) * 32 + sg * 8;
#pragma unroll
            for (int j = 0; j < 8; ++j)
                conv_lds[(posb + j) * 65 + co] = acc[j] + bco;
        }
    __syncthreads();

    if (t < 128) {
        float s = 0.f, ss = 0.f;
#pragma unroll 8
        for (int c = 0; c < 64; ++c) { float v = conv_lds[t * 65 + c]; s += v; ss += v * v; }
        float mean = s * (1.f / 64.f);
        float var = ss * (1.f / 64.f) - mean * mean;
        stats[t] = mean;
        stats[128 + t] = rsqrtf(var + 1e-5f);
    }
    __syncthreads();

    {
        const int wp = t & 15, cog = t >> 4;
#pragma unroll
        for (int j = 0; j < 4; ++j) {
            const int c = cog * 4 + j;
            float sum = 0.f;
#pragma unroll
            for (int pd2 = 0; pd2 < 4; ++pd2)
#pragma unroll
                for (int ww = 0; ww < 2; ++ww) {
                    const int pos = pd2 * 32 + wp * 2 + ww;
                    sum += (conv_lds[pos * 65 + c] - stats[pos]) * stats[128 + pos];
                }
            float y = sum * 0.125f * gamma[c] + beta[c];
            float u = 0.7978845608028654f * (y + 0.044715f * y * y * y);
            float g = 0.5f * y * (1.f + tanhf(u));
            out[(((n * 64 + c) * 16 + dp) * 32 + hp) * 32 + (wq * 16 + wp)] = g;
        }
    }
}

extern "C" void kernel_launch(void* const* d_in, const int* in_sizes, int n_in,
                              void* d_out, int out_size, void* d_ws, size_t ws_size,
                              hipStream_t stream) {
    const float* x = (const float*)d_in[0];
    const float* w = (const float*)d_in[1];
    const float* bias = (const float*)d_in[2];
    const float* gamma = (const float*)d_in[3];
    const float* beta = (const float*)d_in[4];
    float* out = (float*)d_out;

    const size_t need = (size_t)(27 * 64 * 32) * sizeof(unsigned short);
    if (ws_size >= need) {
        unsigned short* wpack = (unsigned short*)d_ws;
        pack_w<<<(27 * 64 * 32 + 255) / 256, 256, 0, stream>>>(w, wpack);
        conv_fused<<<4096, 256, 0, stream>>>(x, wpack, bias, gamma, beta, out);
    } else {
        fused_fallback<<<32768, 256, 0, stream>>>(x, w, bias, gamma, beta, out);
    }
}